// Round 1
// baseline (213.160 us; speedup 1.0000x reference)
//
#include <hip/hip_runtime.h>

#define N_BCH 64
#define N_DIM 64
#define N_COL 32

// ---------------------------------------------------------------------------
// Main kernel: eng[b] = sum_h mtd_hgt[h,b] * exp(-0.5 * sum_c prc*wrap(diff)^2)
// Block = 256 threads. Thread t covers slab elements [4t..4t+3] (batch b0=t>>3)
// and [1024+4t..+3] (batch b1=32+b0). Grid-stride over hills; per-block
// partial eng written to d_ws (no atomics).
// ---------------------------------------------------------------------------
__global__ __launch_bounds__(256) void wtmd_main(
    const float* __restrict__ col_var,
    const float* __restrict__ mtd_cen,
    const float* __restrict__ mtd_prc,
    const float* __restrict__ mtd_hgt,
    const float* __restrict__ pbc,
    const int*   __restrict__ msk,
    float*       __restrict__ partial,   // [gridDim.x][64]
    int n_hil)
{
    const int t  = threadIdx.x;
    const int b0 = t >> 3;          // 0..31
    const int b1 = 32 + b0;         // 32..63
    const int c0 = (4 * t) & 31;    // column base for this thread

    // Preload per-thread constants: col values for our 4 columns (both
    // batches), pbc and 1/pbc.
    float colA[4], colB[4], pb[4], ipb[4];
#pragma unroll
    for (int j = 0; j < 4; ++j) {
        const int c = c0 + j;
        const int m = msk[c];
        colA[j] = col_var[b0 * N_DIM + m];
        colB[j] = col_var[b1 * N_DIM + m];
        const float p = pbc[c];
        pb[j]  = p;
        ipb[j] = (p > 0.f) ? (1.0f / p) : 0.f;
    }

    float accE0 = 0.f, accE1 = 0.f;

    for (int h = blockIdx.x; h < n_hil; h += gridDim.x) {
        const size_t base = (size_t)h * (N_BCH * N_COL) + 4 * (size_t)t;
        const float4 cen4a = *(const float4*)(mtd_cen + base);
        const float4 prc4a = *(const float4*)(mtd_prc + base);
        const float4 cen4b = *(const float4*)(mtd_cen + base + 1024);
        const float4 prc4b = *(const float4*)(mtd_prc + base + 1024);
        const float hg0 = mtd_hgt[(size_t)h * N_BCH + b0];
        const float hg1 = mtd_hgt[(size_t)h * N_BCH + b1];

        const float ca[4] = {cen4a.x, cen4a.y, cen4a.z, cen4a.w};
        const float pa[4] = {prc4a.x, prc4a.y, prc4a.z, prc4a.w};
        const float cb[4] = {cen4b.x, cen4b.y, cen4b.z, cen4b.w};
        const float pbv[4]= {prc4b.x, prc4b.y, prc4b.z, prc4b.w};

        float s0 = 0.f, s1 = 0.f;
#pragma unroll
        for (int j = 0; j < 4; ++j) {
            float d = colA[j] - ca[j];
            if (pb[j] > 0.f) d -= pb[j] * rintf(d * ipb[j]);
            s0 = fmaf(pa[j] * d, d, s0);
            float e = colB[j] - cb[j];
            if (pb[j] > 0.f) e -= pb[j] * rintf(e * ipb[j]);
            s1 = fmaf(pbv[j] * e, e, s1);
        }

        // Butterfly across the 8 lanes of this (h,b) group (lanes share b).
#pragma unroll
        for (int m = 1; m < 8; m <<= 1) {
            s0 += __shfl_xor(s0, m);
            s1 += __shfl_xor(s1, m);
        }

        accE0 += hg0 * __expf(-0.5f * s0);
        accE1 += hg1 * __expf(-0.5f * s1);
    }

    if ((t & 7) == 0) {
        partial[(size_t)blockIdx.x * N_BCH + b0] = accE0;
        partial[(size_t)blockIdx.x * N_BCH + b1] = accE1;
    }
}

// ---------------------------------------------------------------------------
// Epilogue: reduce per-block partials -> eng[64]; write all three outputs.
// out[0..2047]      = col      (64x32)
// out[2048..4095]   = prc_new  (64x32)
// out[4096..4159]   = hgt_wt   (64)
// ---------------------------------------------------------------------------
__global__ __launch_bounds__(256) void wtmd_epi(
    const float* __restrict__ col_var,
    const float* __restrict__ kbt,
    const float* __restrict__ prc,
    const float* __restrict__ hgt,   // scalar
    const float* __restrict__ gam,   // scalar
    const int*   __restrict__ msk,
    const float* __restrict__ partial,
    int nblocks,
    float*       __restrict__ out)
{
    __shared__ float red[256];
    const int t = threadIdx.x;
    const int b = t & 63;
    const int s = t >> 6;   // 0..3 stripes

    float acc = 0.f;
    for (int g = s; g < nblocks; g += 4)
        acc += partial[(size_t)g * N_BCH + b];
    red[t] = acc;
    __syncthreads();

    if (t < 64) {
        const float eng = red[t] + red[t + 64] + red[t + 128] + red[t + 192];
        const float k   = kbt[t];
        const float det = gam[0] * k - k;
        out[4096 + t] = hgt[0] * __expf(-eng / det);
    }

    for (int i = t; i < N_BCH * N_COL; i += 256) {
        const int bb = i >> 5;
        const int c  = i & 31;
        out[i]        = col_var[bb * N_DIM + msk[c]];
        out[2048 + i] = prc[c];
    }
}

extern "C" void kernel_launch(void* const* d_in, const int* in_sizes, int n_in,
                              void* d_out, int out_size, void* d_ws, size_t ws_size,
                              hipStream_t stream) {
    const float* col_var = (const float*)d_in[0];
    const float* mtd_cen = (const float*)d_in[1];
    const float* mtd_prc = (const float*)d_in[2];
    const float* mtd_hgt = (const float*)d_in[3];
    const float* kbt     = (const float*)d_in[4];
    const float* prc     = (const float*)d_in[5];
    const float* hgt     = (const float*)d_in[6];
    const float* gam     = (const float*)d_in[7];
    const float* pbc     = (const float*)d_in[8];
    const int*   msk     = (const int*)d_in[9];
    float* out     = (float*)d_out;
    float* partial = (float*)d_ws;

    const int n_hil = in_sizes[3] / N_BCH;   // mtd_hgt is (n_hil, 64)

    int nblocks = 1024;
    const size_t per_block = (size_t)N_BCH * sizeof(float);
    if (ws_size < (size_t)nblocks * per_block)
        nblocks = (int)(ws_size / per_block);
    if (nblocks < 1) nblocks = 1;
    if (nblocks > n_hil) nblocks = n_hil;

    wtmd_main<<<nblocks, 256, 0, stream>>>(col_var, mtd_cen, mtd_prc, mtd_hgt,
                                           pbc, msk, partial, n_hil);
    wtmd_epi<<<1, 256, 0, stream>>>(col_var, kbt, prc, hgt, gam, msk,
                                    partial, nblocks, out);
}

// Round 2
// 149.844 us; speedup vs baseline: 1.4226x; 1.4226x over previous
//
#include <hip/hip_runtime.h>

#define N_BCH 64
#define N_DIM 64
#define N_COL 32

typedef float f32x4 __attribute__((ext_vector_type(4)));

// ---------------------------------------------------------------------------
// Main kernel: eng[b] = sum_h mtd_hgt[h,b] * exp(-0.5 * sum_c prc*wrap(diff)^2)
// Block = 512 threads (8 waves). Thread t owns 4 columns ((4t)&31) of batch
// t>>3 — one float4 per array per hill, fully coalesced 2 KB/wave/instr.
// Grid-stride over hills; per-block partial eng written transposed to d_ws.
// VGPR target <=64 so 4 blocks/CU = 32 waves/CU (max occupancy).
// ---------------------------------------------------------------------------
__global__ __launch_bounds__(512, 8) void wtmd_main(
    const float* __restrict__ col_var,
    const float* __restrict__ mtd_cen,
    const float* __restrict__ mtd_prc,
    const float* __restrict__ mtd_hgt,
    const float* __restrict__ pbc,
    const int*   __restrict__ msk,
    float*       __restrict__ partial,   // [64][gridDim.x]  (transposed)
    int n_hil)
{
    const int t  = threadIdx.x;     // 0..511
    const int b  = t >> 3;          // 0..63
    const int c0 = (4 * t) & 31;    // column base

    float col[4], pb[4], ipb[4];
#pragma unroll
    for (int j = 0; j < 4; ++j) {
        const int c = c0 + j;
        col[j] = col_var[b * N_DIM + msk[c]];
        const float p = pbc[c];
        pb[j]  = p;
        // when p<=0: ipb=0 -> rintf(0)=0 -> no wrap applied (matches reference)
        ipb[j] = (p > 0.f) ? (1.0f / p) : 0.f;
    }

    float acc = 0.f;
    const int stride = gridDim.x;

    for (int h = blockIdx.x; h < n_hil; h += stride) {
        const size_t base = (size_t)h * (N_BCH * N_COL) + 4 * (size_t)t;
        const f32x4 cen = __builtin_nontemporal_load((const f32x4*)(mtd_cen + base));
        const f32x4 pr  = __builtin_nontemporal_load((const f32x4*)(mtd_prc + base));
        const float hg  = __builtin_nontemporal_load(mtd_hgt + (size_t)h * N_BCH + b);

        float s = 0.f;
#pragma unroll
        for (int j = 0; j < 4; ++j) {
            float d = col[j] - cen[j];
            d -= pb[j] * rintf(d * ipb[j]);
            s = fmaf(pr[j] * d, d, s);
        }

        // reduce across the 8 lanes sharing this batch
#pragma unroll
        for (int m = 1; m < 8; m <<= 1)
            s += __shfl_xor(s, m);

        acc += hg * __expf(-0.5f * s);
    }

    if ((t & 7) == 0)
        partial[(size_t)b * stride + blockIdx.x] = acc;
}

// ---------------------------------------------------------------------------
// Epilogue: reduce per-block partials -> eng[64]; write all three outputs.
// out[0..2047]      = col      (64x32)
// out[2048..4095]   = prc_new  (64x32)
// out[4096..4159]   = hgt_wt   (64)
// partial is [64][nblocks] so the reduce is contiguous float4 loads.
// ---------------------------------------------------------------------------
__global__ __launch_bounds__(256) void wtmd_epi(
    const float* __restrict__ col_var,
    const float* __restrict__ kbt,
    const float* __restrict__ prc,
    const float* __restrict__ hgt,   // scalar
    const float* __restrict__ gam,   // scalar
    const int*   __restrict__ msk,
    const float* __restrict__ partial,
    int nblocks,                      // multiple of 4
    float*       __restrict__ out)
{
    __shared__ float red[256];
    const int t = threadIdx.x;
    const int b = t & 63;
    const int s = t >> 6;   // 0..3 stripes

    const float* row = partial + (size_t)b * nblocks;
    float acc = 0.f;
    for (int g = 4 * s; g < nblocks; g += 16) {
        const f32x4 v = *(const f32x4*)(row + g);
        acc += (v[0] + v[1]) + (v[2] + v[3]);
    }
    red[t] = acc;
    __syncthreads();

    if (t < 64) {
        const float eng = (red[t] + red[t + 64]) + (red[t + 128] + red[t + 192]);
        const float k   = kbt[t];
        const float det = gam[0] * k - k;
        out[4096 + t] = hgt[0] * __expf(-eng / det);
    }

    for (int i = t; i < N_BCH * N_COL; i += 256) {
        const int bb = i >> 5;
        const int c  = i & 31;
        out[i]        = col_var[bb * N_DIM + msk[c]];
        out[2048 + i] = prc[c];
    }
}

extern "C" void kernel_launch(void* const* d_in, const int* in_sizes, int n_in,
                              void* d_out, int out_size, void* d_ws, size_t ws_size,
                              hipStream_t stream) {
    const float* col_var = (const float*)d_in[0];
    const float* mtd_cen = (const float*)d_in[1];
    const float* mtd_prc = (const float*)d_in[2];
    const float* mtd_hgt = (const float*)d_in[3];
    const float* kbt     = (const float*)d_in[4];
    const float* prc     = (const float*)d_in[5];
    const float* hgt     = (const float*)d_in[6];
    const float* gam     = (const float*)d_in[7];
    const float* pbc     = (const float*)d_in[8];
    const int*   msk     = (const int*)d_in[9];
    float* out     = (float*)d_out;
    float* partial = (float*)d_ws;

    const int n_hil = in_sizes[3] / N_BCH;   // mtd_hgt is (n_hil, 64)

    // 1024 blocks x 8 waves = 8192 waves = 32 waves/CU on 256 CUs.
    int nblocks = 1024;
    const size_t per_block = (size_t)N_BCH * sizeof(float);
    if (ws_size < (size_t)nblocks * per_block)
        nblocks = (int)(ws_size / per_block);
    nblocks &= ~3;                // multiple of 4 for float4 epilogue
    if (nblocks < 4) nblocks = 4; // (ws_size is always >= 1KB in practice)

    wtmd_main<<<nblocks, 512, 0, stream>>>(col_var, mtd_cen, mtd_prc, mtd_hgt,
                                           pbc, msk, partial, n_hil);
    wtmd_epi<<<1, 256, 0, stream>>>(col_var, kbt, prc, hgt, gam, msk,
                                    partial, nblocks, out);
}